// Round 10
// baseline (80.955 us; speedup 1.0000x reference)
//
#include <hip/hip_runtime.h>
#include <stdint.h>

// Problem constants
constexpr int Dn = 10000;
constexpr int Bn = 128;
constexpr int Wn = 512;
constexpr int Hn = 128;
constexpr int NTILES = 157;      // ceil(10000/64) d-tiles of N=64
constexpr int REPS = 4;          // instrumentation: repeat idempotent bodies

typedef float  f32x4  __attribute__((ext_vector_type(4)));
typedef short  bf16x8 __attribute__((ext_vector_type(8)));  // 8 bf16 (4 VGPRs)

__device__ inline uint16_t f32_to_bf16(float f) {           // RNE
    uint32_t u = __builtin_bit_cast(uint32_t, f);
    return (uint16_t)((u + 0x7FFFu + ((u >> 16) & 1u)) >> 16);
}
__device__ inline float bf16_to_f32(uint16_t h) {
    uint32_t u = ((uint32_t)h) << 16;
    return __builtin_bit_cast(float, u);
}

// ---------------------------------------------------------------------------
// Kernel 1 (fused pre-pass), body identical to R9, wrapped in a REPS loop.
// Idempotent: each block rewrites its own output slice with the same values.
// ---------------------------------------------------------------------------
__global__ __launch_bounds__(256) void prep(const float* __restrict__ x,
                                            const float* __restrict__ wts,
                                            double* __restrict__ sT64,
                                            uint16_t* __restrict__ aHi,
                                            uint16_t* __restrict__ aLo,
                                            uint32_t* __restrict__ bitsT) {
    __shared__ double red[8][128];
    int bid = blockIdx.x;
    for (int rep = 0; rep < REPS; ++rep) {
        if (bid < 512) {
            int b  = bid >> 2;
            int w0 = (bid & 3) << 7;            // w-quarter base
            int wc = threadIdx.x & 31;          // float4 column: w = w0 + wc*4
            int hs = threadIdx.x >> 5;          // 8 h-slices of 16
            const f32x4* p = (const f32x4*)(x + (size_t)b * (Hn * Wn)
                                              + (size_t)(hs * 16) * Wn + w0) + wc;
            double a0 = 0, a1 = 0, a2 = 0, a3 = 0;
            #pragma unroll
            for (int h = 0; h < 16; ++h) {
                f32x4 f = p[(size_t)h * (Wn / 4)];
                a0 += (double)f.x; a1 += (double)f.y;
                a2 += (double)f.z; a3 += (double)f.w;
            }
            red[hs][wc * 4 + 0] = a0;
            red[hs][wc * 4 + 1] = a1;
            red[hs][wc * 4 + 2] = a2;
            red[hs][wc * 4 + 3] = a3;
            __syncthreads();
            if (threadIdx.x < 128) {
                int wl = threadIdx.x;
                double s = 0.0;
                #pragma unroll
                for (int k = 0; k < 8; ++k) s += red[k][wl];   // fixed order
                int w = w0 + wl;
                sT64[(size_t)b * Wn + w] = s;
                float s32 = (float)s;
                uint16_t hi = f32_to_bf16(s32);
                float hif = bf16_to_f32(hi);
                uint16_t lo = f32_to_bf16(s32 - hif);          // residual capture
                int ktile = w >> 5;
                int mtile = b >> 4;
                int lane  = (b & 15) | (((w >> 3) & 3) << 4);
                int j     = w & 7;
                size_t idx = (size_t)((ktile * 8 + mtile) * 64 + lane) * 8 + j;
                aHi[idx] = hi;
                aLo[idx] = lo;
            }
            __syncthreads();                    // LDS reuse across reps
        } else {
            int idx = (bid - 512) * 256 + (int)threadIdx.x;    // 0 .. 159999
            int g = idx / Dn;
            int d = idx - g * Dn;
            uint32_t m = 0;
            #pragma unroll
            for (int j = 0; j < 32; ++j)
                m |= (wts[(size_t)(g * 32 + j) * Dn + d] > 0.0f) ? (1u << j) : 0u;
            bitsT[(size_t)d * 16 + g] = m;                     // transposed layout
        }
    }
}

// ---------------------------------------------------------------------------
// Kernel 2: MFMA GEMM + sign + inline wave-cooperative exact fixup,
// body identical to R9, wrapped in a REPS loop (idempotent, no barriers,
// no atomics).
// ---------------------------------------------------------------------------
__global__ __launch_bounds__(256) void gemm_mfma(const uint32_t* __restrict__ bitsT,
                                                 const uint16_t* __restrict__ aHi,
                                                 const uint16_t* __restrict__ aLo,
                                                 const double* __restrict__ sT64,
                                                 float* __restrict__ out) {
    int lane = (int)threadIdx.x & 63;
    int wid  = (int)threadIdx.x >> 6;
    int t    = blockIdx.x * 4 + wid;     // d-tile index
    if (t >= NTILES) return;             // no barriers in this kernel
    int mt = blockIdx.y;                 // b-range mt*16..+15
    int ln = lane & 15;
    int lh = lane >> 4;
    int sh = lh * 8;
    int dbase = t * 64;

    for (int rep = 0; rep < REPS; ++rep) {
        // Load all 4 nt x 16 g mask words for this tile (contiguous 64B per d).
        uint32_t wrd[4][16];
        #pragma unroll
        for (int nt = 0; nt < 4; ++nt) {
            int d = dbase + nt * 16 + ln;
            int dc = d < Dn ? d : Dn - 1;    // clamp (tail tile only)
            const uint4* wp = (const uint4*)(bitsT + (size_t)dc * 16);
            #pragma unroll
            for (int q = 0; q < 4; ++q) {
                uint4 v = wp[q];
                wrd[nt][4 * q + 0] = v.x; wrd[nt][4 * q + 1] = v.y;
                wrd[nt][4 * q + 2] = v.z; wrd[nt][4 * q + 3] = v.w;
            }
        }

        f32x4 acc[4];
        #pragma unroll
        for (int nt = 0; nt < 4; ++nt) acc[nt] = (f32x4){0.f, 0.f, 0.f, 0.f};

        const bf16x8* Ah = (const bf16x8*)aHi;
        const bf16x8* Al = (const bf16x8*)aLo;

        #pragma unroll
        for (int g = 0; g < 16; ++g) {
            int fi = (g * 8 + mt) * 64 + lane;
            bf16x8 ah = Ah[fi];              // L2-resident (A = 256 KB total)
            bf16x8 al = Al[fi];
            #pragma unroll
            for (int nt = 0; nt < 4; ++nt) {
                uint32_t t8 = (wrd[nt][g] >> sh) & 0xFFu;
                // bit=1 -> +1.0 (0x3F80), bit=0 -> -1.0 (0xBF80): XOR sign bit
                int bw0 = (int)(0xBF80BF80u ^ (((t8 & 1u) << 15) | ((t8 & 2u) << 30)));
                int bw1 = (int)(0xBF80BF80u ^ ((((t8 >> 2) & 1u) << 15) | (((t8 >> 3) & 1u) << 31)));
                int bw2 = (int)(0xBF80BF80u ^ ((((t8 >> 4) & 1u) << 15) | (((t8 >> 5) & 1u) << 31)));
                int bw3 = (int)(0xBF80BF80u ^ ((((t8 >> 6) & 1u) << 15) | (((t8 >> 7) & 1u) << 31)));
                union { int i[4]; bf16x8 v; } bu;
                bu.i[0] = bw0; bu.i[1] = bw1; bu.i[2] = bw2; bu.i[3] = bw3;
                bf16x8 bf = bu.v;
                acc[nt] = __builtin_amdgcn_mfma_f32_16x16x32_bf16(ah, bf, acc[nt], 0, 0, 0);
                acc[nt] = __builtin_amdgcn_mfma_f32_16x16x32_bf16(al, bf, acc[nt], 0, 0, 0);
            }
        }

        // Epilogue. C/D layout: col = lane&15, row = (lane>>4)*4 + reg.
        #pragma unroll
        for (int nt = 0; nt < 4; ++nt) {
            int d = dbase + nt * 16 + ln;
            bool valid = d < Dn;
            #pragma unroll
            for (int r = 0; r < 4; ++r) {
                int b = mt * 16 + lh * 4 + r;
                float v = acc[nt][r];
                if (valid) out[(size_t)b * Dn + d] = v > 0.0f ? 1.0f : -1.0f;
                unsigned long long mask = __ballot(valid && fabsf(v) <= 0.25f);
                while (mask) {
                    int l = __ffsll((long long)mask) - 1;
                    mask &= mask - 1;
                    int bl = mt * 16 + (l >> 4) * 4 + r;
                    int dl = dbase + nt * 16 + (l & 15);
                    const double* srow = sT64 + (size_t)bl * Wn;
                    double a = 0.0;
                    #pragma unroll
                    for (int k = 0; k < 8; ++k) {
                        int w = lane + 64 * k;
                        uint32_t mw = bitsT[(size_t)dl * 16 + (w >> 5)];
                        double s = srow[w];
                        a += ((mw >> (w & 31)) & 1u) ? s : -s;
                    }
                    #pragma unroll
                    for (int off = 32; off >= 1; off >>= 1)
                        a += __shfl_xor(a, off, 64);
                    if (lane == l)          // owner overwrites its own guess
                        out[(size_t)bl * Dn + dl] = (a > 0.0) ? 1.0f : ((a < 0.0) ? -1.0f : 0.0f);
                }
            }
        }
    }
}

// ---------------------------------------------------------------------------
extern "C" void kernel_launch(void* const* d_in, const int* in_sizes, int n_in,
                              void* d_out, int out_size, void* d_ws, size_t ws_size,
                              hipStream_t stream) {
    const float* x   = (const float*)d_in[0];   // (128,128,512) f32
    const float* wts = (const float*)d_in[1];   // (512,10000)  f32, values +-1
    float* out = (float*)d_out;                 // (128,10000)  f32 signs
    char* ws = (char*)d_ws;

    // workspace layout (~1.43 MB total)
    double*   sT64  = (double*)(ws);                  // 128*512*8 = 524,288 B
    uint16_t* aHi   = (uint16_t*)(ws + 524288);       // 65536*2   = 131,072 B
    uint16_t* aLo   = (uint16_t*)(ws + 655360);       // 131,072 B
    uint32_t* bitsT = (uint32_t*)(ws + 786432);       // 10000*16*4 = 640,000 B

    prep<<<1137, 256, 0, stream>>>(x, wts, sT64, aHi, aLo, bitsT);
    gemm_mfma<<<dim3(40, 8), 256, 0, stream>>>(bitsT, aHi, aLo, sT64, out);
}

// Round 11
// 28.051 us; speedup vs baseline: 2.8860x; 2.8860x over previous
//
#include <hip/hip_runtime.h>
#include <stdint.h>

// Problem constants
constexpr int Dn = 10000;
constexpr int Bn = 128;
constexpr int Wn = 512;
constexpr int Hn = 128;
constexpr int NTILES = 157;      // ceil(10000/64) d-tiles of N=64

typedef float  f32x4  __attribute__((ext_vector_type(4)));
typedef short  bf16x8 __attribute__((ext_vector_type(8)));  // 8 bf16 (4 VGPRs)

__device__ inline uint16_t f32_to_bf16(float f) {           // RNE
    uint32_t u = __builtin_bit_cast(uint32_t, f);
    return (uint16_t)((u + 0x7FFFu + ((u >> 16) & 1u)) >> 16);
}
__device__ inline float bf16_to_f32(uint16_t h) {
    uint32_t u = ((uint32_t)h) << 16;
    return __builtin_bit_cast(float, u);
}

// ---------------------------------------------------------------------------
// Kernel 1 (fused pre-pass) — identical to R9 (proven absmax 0):
//  blocks 0..511  : h-reduction -> sT64[b][w] + aHi/aLo (MFMA A-fragment
//                   layout, bf16 hi/lo split).
//  blocks 512..1136: pack W signs transposed: bitsT[d*16+g] bit j =
//                   (W[g*32+j][d] > 0), 64 B contiguous per d.
// ---------------------------------------------------------------------------
__global__ __launch_bounds__(256) void prep(const float* __restrict__ x,
                                            const float* __restrict__ wts,
                                            double* __restrict__ sT64,
                                            uint16_t* __restrict__ aHi,
                                            uint16_t* __restrict__ aLo,
                                            uint32_t* __restrict__ bitsT) {
    int bid = blockIdx.x;
    if (bid < 512) {
        int b  = bid >> 2;
        int w0 = (bid & 3) << 7;            // w-quarter base
        int wc = threadIdx.x & 31;          // float4 column: w = w0 + wc*4
        int hs = threadIdx.x >> 5;          // 8 h-slices of 16
        const f32x4* p = (const f32x4*)(x + (size_t)b * (Hn * Wn)
                                          + (size_t)(hs * 16) * Wn + w0) + wc;
        double a0 = 0, a1 = 0, a2 = 0, a3 = 0;
        #pragma unroll
        for (int h = 0; h < 16; ++h) {
            f32x4 f = p[(size_t)h * (Wn / 4)];
            a0 += (double)f.x; a1 += (double)f.y;
            a2 += (double)f.z; a3 += (double)f.w;
        }
        __shared__ double red[8][128];
        red[hs][wc * 4 + 0] = a0;
        red[hs][wc * 4 + 1] = a1;
        red[hs][wc * 4 + 2] = a2;
        red[hs][wc * 4 + 3] = a3;
        __syncthreads();
        if (threadIdx.x < 128) {
            int wl = threadIdx.x;
            double s = 0.0;
            #pragma unroll
            for (int k = 0; k < 8; ++k) s += red[k][wl];   // fixed order
            int w = w0 + wl;
            sT64[(size_t)b * Wn + w] = s;
            float s32 = (float)s;
            uint16_t hi = f32_to_bf16(s32);
            float hif = bf16_to_f32(hi);
            uint16_t lo = f32_to_bf16(s32 - hif);          // residual capture
            int ktile = w >> 5;
            int mtile = b >> 4;
            int lane  = (b & 15) | (((w >> 3) & 3) << 4);
            int j     = w & 7;
            size_t idx = (size_t)((ktile * 8 + mtile) * 64 + lane) * 8 + j;
            aHi[idx] = hi;
            aLo[idx] = lo;
        }
    } else {
        int idx = (bid - 512) * 256 + (int)threadIdx.x;    // 0 .. 159999 exactly
        int g = idx / Dn;
        int d = idx - g * Dn;
        uint32_t m = 0;
        #pragma unroll
        for (int j = 0; j < 32; ++j)
            m |= (wts[(size_t)(g * 32 + j) * Dn + d] > 0.0f) ? (1u << j) : 0u;
        bitsT[(size_t)d * 16 + g] = m;                     // transposed layout
    }
}

// ---------------------------------------------------------------------------
// Kernel 2: MFMA GEMM with LDS-staged A + sign + inline exact fixup.
// grid (40, 8), 256 threads = 4 waves, all sharing mt = blockIdx.y.
// Stage: the block's 32 KB A-slice (aHi+aLo for this mt, all 16 g) is loaded
// cooperatively into LDS (8 uint4/thread), one barrier. K-loop reads A via
// conflict-free ds_read_b128 (16 B/lane) -- no exposed L2 latency chains,
// VGPR stays ~130. Wave w owns d-tile t = bx*4+w (clamped to NTILES-1 for
// the 3 tail waves: duplicate deterministic work, benign duplicate writes).
// Per g: 2 ds_read + synthesize +-1 bf16 B-frags from mask bits + 8 MFMA.
// Epilogue: sign store + __ballot ambiguous (|v|<=0.25), wave-cooperative
// fp64 exact recompute from sT64/bitsT, owner-lane overwrite (proven R9).
// ---------------------------------------------------------------------------
__global__ __launch_bounds__(256) void gemm_mfma(const uint32_t* __restrict__ bitsT,
                                                 const uint16_t* __restrict__ aHi,
                                                 const uint16_t* __restrict__ aLo,
                                                 const double* __restrict__ sT64,
                                                 float* __restrict__ out) {
    __shared__ uint4 shA[2048];              // 32 KB: chunks 0..15 hi, 16..31 lo
    int tid  = (int)threadIdx.x;
    int lane = tid & 63;
    int wid  = tid >> 6;
    int mt   = blockIdx.y;                   // b-range mt*16..+15

    // --- cooperative A staging (chunk g = 1 KB = 64 lanes x 16 B) ---
    const uint4* AhU = (const uint4*)aHi;    // fragment (g,mt): base (g*8+mt)*64
    const uint4* AlU = (const uint4*)aLo;
    #pragma unroll
    for (int c = 0; c < 8; ++c) {
        int e = tid + 256 * c;               // 0..2047
        int chunk = e >> 6;                  // 0..31
        int l = e & 63;
        int g = chunk & 15;
        const uint4* src = (chunk < 16 ? AhU : AlU) + (size_t)(g * 8 + mt) * 64 + l;
        shA[e] = *src;
    }

    // --- per-wave d-tile & mask preload (independent of staging) ---
    int t = blockIdx.x * 4 + wid;
    if (t >= NTILES) t = NTILES - 1;         // tail waves duplicate tile 156
    int ln = lane & 15;
    int lh = lane >> 4;
    int sh = lh * 8;
    int dbase = t * 64;

    uint32_t wrd[4][16];
    #pragma unroll
    for (int nt = 0; nt < 4; ++nt) {
        int d = dbase + nt * 16 + ln;
        int dc = d < Dn ? d : Dn - 1;        // clamp (tail tile only)
        const uint4* wp = (const uint4*)(bitsT + (size_t)dc * 16);
        #pragma unroll
        for (int q = 0; q < 4; ++q) {
            uint4 v = wp[q];
            wrd[nt][4 * q + 0] = v.x; wrd[nt][4 * q + 1] = v.y;
            wrd[nt][4 * q + 2] = v.z; wrd[nt][4 * q + 3] = v.w;
        }
    }

    __syncthreads();                         // A staged

    f32x4 acc[4];
    #pragma unroll
    for (int nt = 0; nt < 4; ++nt) acc[nt] = (f32x4){0.f, 0.f, 0.f, 0.f};

    const bf16x8* shAv = (const bf16x8*)shA;
    #pragma unroll
    for (int g = 0; g < 16; ++g) {
        bf16x8 ah = shAv[g * 64 + lane];             // ds_read_b128, no conflict
        bf16x8 al = shAv[(16 + g) * 64 + lane];
        #pragma unroll
        for (int nt = 0; nt < 4; ++nt) {
            uint32_t t8 = (wrd[nt][g] >> sh) & 0xFFu;
            // bit=1 -> +1.0 (0x3F80), bit=0 -> -1.0 (0xBF80): XOR sign bit
            int bw0 = (int)(0xBF80BF80u ^ (((t8 & 1u) << 15) | ((t8 & 2u) << 30)));
            int bw1 = (int)(0xBF80BF80u ^ ((((t8 >> 2) & 1u) << 15) | (((t8 >> 3) & 1u) << 31)));
            int bw2 = (int)(0xBF80BF80u ^ ((((t8 >> 4) & 1u) << 15) | (((t8 >> 5) & 1u) << 31)));
            int bw3 = (int)(0xBF80BF80u ^ ((((t8 >> 6) & 1u) << 15) | (((t8 >> 7) & 1u) << 31)));
            union { int i[4]; bf16x8 v; } bu;
            bu.i[0] = bw0; bu.i[1] = bw1; bu.i[2] = bw2; bu.i[3] = bw3;
            bf16x8 bf = bu.v;
            acc[nt] = __builtin_amdgcn_mfma_f32_16x16x32_bf16(ah, bf, acc[nt], 0, 0, 0);
            acc[nt] = __builtin_amdgcn_mfma_f32_16x16x32_bf16(al, bf, acc[nt], 0, 0, 0);
        }
    }

    // Epilogue. C/D layout: col = lane&15, row = (lane>>4)*4 + reg.
    #pragma unroll
    for (int nt = 0; nt < 4; ++nt) {
        int d = dbase + nt * 16 + ln;
        bool valid = d < Dn;
        #pragma unroll
        for (int r = 0; r < 4; ++r) {
            int b = mt * 16 + lh * 4 + r;
            float v = acc[nt][r];
            if (valid) out[(size_t)b * Dn + d] = v > 0.0f ? 1.0f : -1.0f;
            unsigned long long mask = __ballot(valid && fabsf(v) <= 0.25f);
            while (mask) {
                int l = __ffsll((long long)mask) - 1;
                mask &= mask - 1;
                int bl = mt * 16 + (l >> 4) * 4 + r;
                int dl = dbase + nt * 16 + (l & 15);
                const double* srow = sT64 + (size_t)bl * Wn;
                double a = 0.0;
                #pragma unroll
                for (int k = 0; k < 8; ++k) {
                    int w = lane + 64 * k;
                    uint32_t mw = bitsT[(size_t)dl * 16 + (w >> 5)];
                    double s = srow[w];
                    a += ((mw >> (w & 31)) & 1u) ? s : -s;
                }
                #pragma unroll
                for (int off = 32; off >= 1; off >>= 1)
                    a += __shfl_xor(a, off, 64);
                if (lane == l)          // owner overwrites its own guess
                    out[(size_t)bl * Dn + dl] = (a > 0.0) ? 1.0f : ((a < 0.0) ? -1.0f : 0.0f);
            }
        }
    }
}

// ---------------------------------------------------------------------------
extern "C" void kernel_launch(void* const* d_in, const int* in_sizes, int n_in,
                              void* d_out, int out_size, void* d_ws, size_t ws_size,
                              hipStream_t stream) {
    const float* x   = (const float*)d_in[0];   // (128,128,512) f32
    const float* wts = (const float*)d_in[1];   // (512,10000)  f32, values +-1
    float* out = (float*)d_out;                 // (128,10000)  f32 signs
    char* ws = (char*)d_ws;

    // workspace layout (~1.43 MB total)
    double*   sT64  = (double*)(ws);                  // 128*512*8 = 524,288 B
    uint16_t* aHi   = (uint16_t*)(ws + 524288);       // 65536*2   = 131,072 B
    uint16_t* aLo   = (uint16_t*)(ws + 655360);       // 131,072 B
    uint32_t* bitsT = (uint32_t*)(ws + 786432);       // 10000*16*4 = 640,000 B

    prep<<<1137, 256, 0, stream>>>(x, wts, sT64, aHi, aLo, bitsT);
    gemm_mfma<<<dim3(40, 8), 256, 0, stream>>>(bitsT, aHi, aLo, sT64, out);
}